// Round 9
// baseline (276.929 us; speedup 1.0000x reference)
//
#include <hip/hip_runtime.h>

typedef unsigned int u32;
typedef int i32x4 __attribute__((ext_vector_type(4)));
typedef int i32x16 __attribute__((ext_vector_type(16)));

// ws layout (bytes):
//   [0..3]      amax (float)
//   [64..1087]  256 partial maxima (float)
//   [2048..]    Wq2: fragment-major i8 weights, 768 KB:
//               addr = nt*24576 + kc*1024 + c*32 + kb
//               (n = nt*32+c in [0,1024), k = kc*32+kb in [0,768))
//               -> a wave's MFMA B-fragment (32 cols x 32 k) is 2 KB contiguous
#define WQ_OFF 2048

// ---------------------------------------------------------------------------
// absmax two-stage tree (no atomics)
// ---------------------------------------------------------------------------
__global__ __launch_bounds__(256) void amax_stage1(const float* __restrict__ W,
                                                   float* __restrict__ part) {
    int t = blockIdx.x * 256 + threadIdx.x;
    float v = 0.0f;
#pragma unroll
    for (int k = 0; k < 12; ++k) v = fmaxf(v, fabsf(W[t + (k << 16)]));
#pragma unroll
    for (int d = 32; d >= 1; d >>= 1) v = fmaxf(v, __shfl_xor(v, d));
    __shared__ float sm[4];
    if ((threadIdx.x & 63) == 0) sm[threadIdx.x >> 6] = v;
    __syncthreads();
    if (threadIdx.x == 0)
        part[blockIdx.x] = fmaxf(fmaxf(sm[0], sm[1]), fmaxf(sm[2], sm[3]));
}

__global__ __launch_bounds__(256) void amax_stage2(const float* __restrict__ part,
                                                   float* __restrict__ amax) {
    float v = part[threadIdx.x];
#pragma unroll
    for (int d = 32; d >= 1; d >>= 1) v = fmaxf(v, __shfl_xor(v, d));
    __shared__ float sm[4];
    if ((threadIdx.x & 63) == 0) sm[threadIdx.x >> 6] = v;
    __syncthreads();
    if (threadIdx.x == 0)
        amax[0] = fmaxf(fmaxf(sm[0], sm[1]), fmaxf(sm[2], sm[3]));
}

// ---------------------------------------------------------------------------
// quantize W_in [1024][768] f32 -> Wq2 fragment-major i8 (see layout above)
// 1024 blocks (one per n-row) x 192 threads (one per 4-k dword): coalesced
// read, permuted write.
// ---------------------------------------------------------------------------
__global__ __launch_bounds__(192) void quant_k(const float* __restrict__ W,
                                               const float* __restrict__ amax,
                                               u32* __restrict__ Wq4) {
    const int n = blockIdx.x, kd = threadIdx.x;     // kd: dword index 0..191
    float s = 127.0f / amax[0];
    float4 v = ((const float4*)(W + n * 768))[kd];
    int a0 = (int)rintf(v.x * s), a1 = (int)rintf(v.y * s);
    int a2 = (int)rintf(v.z * s), a3 = (int)rintf(v.w * s);
    u32 wq = (u32)(a0 & 0xFF) | ((u32)(a1 & 0xFF) << 8) |
             ((u32)(a2 & 0xFF) << 16) | ((u32)(a3 & 0xFF) << 24);
    const int nt = n >> 5, c = n & 31, kc = kd >> 3, kb4 = kd & 7;
    Wq4[nt * 6144 + kc * 256 + c * 8 + kb4] = wq;
}

// ---------------------------------------------------------------------------
// Fused forward — ZERO-barrier main loop, B direct from L2.
// 128 threads = 2 waves per block; block owns 32 rows; each wave owns an
// N-half (512 cols = 8 chunks of 64 = 2 n-tiles each).
// A (binary x) packed once to a 3 KB LDS bit-panel by both waves, then each
// lane holds its 12-dword row-bitmask in regs; expanded to i8 frags in-loop.
// B fragments loaded per-MFMA from Wq2 (L2-resident, coalesced 2 KB/wave).
// grid = 2048 -> 8 blocks/CU, 16 waves/CU at launch_bounds(128,8) (VGPR<=128).
// ---------------------------------------------------------------------------
__global__ __launch_bounds__(128, 8) void nnue_fwd(
    const float* __restrict__ x,       // [B][768], values in {0,1}
    const signed char* __restrict__ Wq2,
    const float* __restrict__ amax,
    const float* __restrict__ b_in,    // [1024]
    const float* __restrict__ W_h,     // [8][1024]
    const float* __restrict__ b_h,     // [8]
    const float* __restrict__ W_psqt,  // [768]
    float* __restrict__ out) {         // [B]

    __shared__ u32   abits[32][2][12]; // [row][k-half hi][dword]
    __shared__ int   bmeta[32];
    __shared__ float pmeta[32];
    __shared__ float comb[32][2];

    const int t = threadIdx.x;
    const size_t row0 = (size_t)blockIdx.x << 5;

    // ---- A phase: 4 threads per row pack x-bits, popcount, psqt ---------
    {
        const int row = t >> 2, q = t & 3;          // q: K-quarter (192 k)
        const float4* xr = (const float4*)(x + (row0 + row) * 768) + q * 48;
        const float4* pw = (const float4*)W_psqt + q * 48;
        u32 csum = 0;
        float ps = 0.0f;
#define PKB(f) ((__float_as_uint(f.x) >> 29)         |                      \
                ((__float_as_uint(f.y) >> 29) << 8)  |                      \
                ((__float_as_uint(f.z) >> 29) << 16) |                      \
                ((__float_as_uint(f.w) >> 29) << 24))
#pragma unroll
        for (int i3 = 0; i3 < 3; ++i3) {
#pragma unroll
            for (int hi = 0; hi < 2; ++hi) {
                u32 dw = 0;
#pragma unroll
                for (int dl = 0; dl < 2; ++dl) {
                    u32 m16 = 0;
#pragma unroll
                    for (int jj = 0; jj < 4; ++jj) {
                        // local float4 idx: k_loc = 64*i3 + 32*dl + 16*hi + 4*jj
                        int fi = i3 * 16 + dl * 8 + hi * 4 + jj;
                        float4 f = xr[fi], p = pw[fi];
                        u32 d = PKB(f);
                        csum += d;                  // byte sums <= 48
                        ps = fmaf(f.x, p.x, ps); ps = fmaf(f.y, p.y, ps);
                        ps = fmaf(f.z, p.z, ps); ps = fmaf(f.w, p.w, ps);
                        m16 |= ((d * 0x01020408u) >> 24) << (jj * 4);
                    }
                    dw |= m16 << (dl * 16);
                }
                abits[row][hi][3 * q + i3] = dw;    // dword i: ks=2i,2i+1
            }
        }
#undef PKB
        int cnt = (csum & 0xFF) + ((csum >> 8) & 0xFF) +
                  ((csum >> 16) & 0xFF) + (csum >> 24);
        cnt += __shfl_xor(cnt, 1); cnt += __shfl_xor(cnt, 2);
        ps  += __shfl_xor(ps, 1);  ps  += __shfl_xor(ps, 2);
        if (q == 0) { bmeta[row] = (cnt - 1) >> 2; pmeta[row] = ps; }
    }
    __syncthreads();            // the ONLY pre-loop barrier

    // ---- per-lane setup -------------------------------------------------
    const int l = t & 63, w = t >> 6;   // 2 waves: w = N-half
    const int cl = l & 31, hi = l >> 5;

    u32 Ab[12];
    {
        uint4 A0 = *(const uint4*)&abits[cl][hi][0];
        uint4 A1 = *(const uint4*)&abits[cl][hi][4];
        uint4 A2 = *(const uint4*)&abits[cl][hi][8];
        Ab[0] = A0.x; Ab[1] = A0.y; Ab[2]  = A0.z; Ab[3]  = A0.w;
        Ab[4] = A1.x; Ab[5] = A1.y; Ab[6]  = A1.z; Ab[7]  = A1.w;
        Ab[8] = A2.x; Ab[9] = A2.y; Ab[10] = A2.z; Ab[11] = A2.w;
    }

    int whoff[16];
#pragma unroll
    for (int g = 0; g < 16; ++g) {
        int er = (g & 3) + ((g >> 2) << 3) + (hi << 2);  // C-row for acc[g]
        whoff[g] = bmeta[er] << 10;                      // bucket * 1024
    }

    const float sc = amax[0] * (1.0f / 127.0f);
    float rs[16];
#pragma unroll
    for (int g = 0; g < 16; ++g) rs[g] = 0.0f;

    // wave's B base: n-tile nt = w*16, this lane's (col, k-half) slot
    const signed char* bbase = Wq2 + (size_t)(w << 4) * 24576
                                   + (cl << 5) + (hi << 4);

    // ---- main loop: 8 chunks x 64 cols, NO barriers ---------------------
    for (int c = 0; c < 8; ++c) {
        i32x16 acc0 = {0,0,0,0,0,0,0,0,0,0,0,0,0,0,0,0};
        i32x16 acc1 = {0,0,0,0,0,0,0,0,0,0,0,0,0,0,0,0};
        const signed char* bp0 = bbase + (size_t)(c << 1) * 24576;
        const signed char* bp1 = bp0 + 24576;
#pragma unroll
        for (int ks = 0; ks < 24; ++ks) {
            u32 pair = Ab[ks >> 1];
            asm volatile("" : "+v"(pair));      // defeat cross-chunk CSE
            u32 m = (ks & 1) ? (pair >> 16) : (pair & 0xFFFFu);
            i32x4 af;
            af[0] = (int)(((m         & 0xFu) * 0x00204081u) & 0x01010101u);
            af[1] = (int)((((m >> 4)  & 0xFu) * 0x00204081u) & 0x01010101u);
            af[2] = (int)((((m >> 8)  & 0xFu) * 0x00204081u) & 0x01010101u);
            af[3] = (int)((((m >> 12)       ) * 0x00204081u) & 0x01010101u);
            i32x4 b0 = *(const i32x4*)(bp0 + (ks << 10));
            i32x4 b1 = *(const i32x4*)(bp1 + (ks << 10));
            acc0 = __builtin_amdgcn_mfma_i32_32x32x32_i8(af, b0, acc0, 0, 0, 0);
            acc1 = __builtin_amdgcn_mfma_i32_32x32x32_i8(af, b1, acc1, 0, 0, 0);
        }
        // fused epilogue (W_h reads are wave-uniform offset + lane col ->
        // coalesced 128B, L1-hot)
        const int col0 = (w << 9) + (c << 6) + cl;
        const float bi0 = b_in[col0], bi1 = b_in[col0 + 32];
#pragma unroll
        for (int g = 0; g < 16; ++g) {
            float h0 = fminf(fmaxf(fmaf((float)acc0[g], sc, bi0), 0.f), 1.f);
            float h1 = fminf(fmaxf(fmaf((float)acc1[g], sc, bi1), 0.f), 1.f);
            rs[g] = fmaf(h0, W_h[whoff[g] + col0], rs[g]);
            rs[g] = fmaf(h1, W_h[whoff[g] + col0 + 32], rs[g]);
        }
    }

    // ---- reduce over 32 col-lanes, combine the two N-halves -------------
#pragma unroll
    for (int g = 0; g < 16; ++g) {
#pragma unroll
        for (int d = 1; d < 32; d <<= 1) rs[g] += __shfl_xor(rs[g], d);
    }
    if (cl == 0) {
#pragma unroll
        for (int g = 0; g < 16; ++g) {
            int er = (g & 3) + ((g >> 2) << 3) + (hi << 2);
            comb[er][w] = rs[g];
        }
    }
    __syncthreads();
    if (t < 32) {
        out[row0 + t] = comb[t][0] + comb[t][1] + pmeta[t] + b_h[bmeta[t]];
    }
}

extern "C" void kernel_launch(void* const* d_in, const int* in_sizes, int n_in,
                              void* d_out, int out_size, void* d_ws, size_t ws_size,
                              hipStream_t stream) {
    const float* x      = (const float*)d_in[0];
    const float* W_in   = (const float*)d_in[1];
    const float* b_in   = (const float*)d_in[2];
    const float* W_h    = (const float*)d_in[3];
    const float* b_h    = (const float*)d_in[4];
    const float* W_psqt = (const float*)d_in[5];
    float* out = (float*)d_out;

    float* amax = (float*)d_ws;
    float* part = (float*)((char*)d_ws + 64);
    signed char* Wq2 = (signed char*)d_ws + WQ_OFF;     // 768 KB

    amax_stage1<<<256, 256, 0, stream>>>(W_in, part);
    amax_stage2<<<1, 256, 0, stream>>>(part, amax);
    quant_k<<<1024, 192, 0, stream>>>(W_in, amax, (u32*)Wq2);

    int B = out_size;                   // 65536
    nnue_fwd<<<B / 32, 128, 0, stream>>>(x, Wq2, amax, b_in, W_h, b_h,
                                         W_psqt, out);
}

// Round 10
// 177.253 us; speedup vs baseline: 1.5623x; 1.5623x over previous
//
#include <hip/hip_runtime.h>

typedef unsigned int u32;
typedef int i32x4 __attribute__((ext_vector_type(4)));
typedef int i32x16 __attribute__((ext_vector_type(16)));

// ws layout (bytes):
//   [0..3]      amax (float)
//   [64..1087]  256 partial maxima (float)
//   [2048..]    Wq2: fragment-major i8 weights, 768 KB:
//               addr = nt*24576 + kc*1024 + c*32 + kb
//               (n = nt*32+c in [0,1024), k = kc*32+kb in [0,768))
//               -> a wave's MFMA B-fragment (32 cols x 32 k) is 1 KB/lane-set,
//                  fully coalesced dwordx4 per lane, L2-resident.
#define WQ_OFF 2048

// ---------------------------------------------------------------------------
// absmax two-stage tree (no atomics)
// ---------------------------------------------------------------------------
__global__ __launch_bounds__(256) void amax_stage1(const float* __restrict__ W,
                                                   float* __restrict__ part) {
    int t = blockIdx.x * 256 + threadIdx.x;
    float v = 0.0f;
#pragma unroll
    for (int k = 0; k < 12; ++k) v = fmaxf(v, fabsf(W[t + (k << 16)]));
#pragma unroll
    for (int d = 32; d >= 1; d >>= 1) v = fmaxf(v, __shfl_xor(v, d));
    __shared__ float sm[4];
    if ((threadIdx.x & 63) == 0) sm[threadIdx.x >> 6] = v;
    __syncthreads();
    if (threadIdx.x == 0)
        part[blockIdx.x] = fmaxf(fmaxf(sm[0], sm[1]), fmaxf(sm[2], sm[3]));
}

__global__ __launch_bounds__(256) void amax_stage2(const float* __restrict__ part,
                                                   float* __restrict__ amax) {
    float v = part[threadIdx.x];
#pragma unroll
    for (int d = 32; d >= 1; d >>= 1) v = fmaxf(v, __shfl_xor(v, d));
    __shared__ float sm[4];
    if ((threadIdx.x & 63) == 0) sm[threadIdx.x >> 6] = v;
    __syncthreads();
    if (threadIdx.x == 0)
        amax[0] = fmaxf(fmaxf(sm[0], sm[1]), fmaxf(sm[2], sm[3]));
}

// ---------------------------------------------------------------------------
// quantize W_in [1024][768] f32 -> Wq2 fragment-major i8 (validated r9)
// ---------------------------------------------------------------------------
__global__ __launch_bounds__(192) void quant_k(const float* __restrict__ W,
                                               const float* __restrict__ amax,
                                               u32* __restrict__ Wq4) {
    const int n = blockIdx.x, kd = threadIdx.x;     // kd: dword index 0..191
    float s = 127.0f / amax[0];
    float4 v = ((const float4*)(W + n * 768))[kd];
    int a0 = (int)rintf(v.x * s), a1 = (int)rintf(v.y * s);
    int a2 = (int)rintf(v.z * s), a3 = (int)rintf(v.w * s);
    u32 wq = (u32)(a0 & 0xFF) | ((u32)(a1 & 0xFF) << 8) |
             ((u32)(a2 & 0xFF) << 16) | ((u32)(a3 & 0xFF) << 24);
    const int nt = n >> 5, c = n & 31, kc = kd >> 3, kb4 = kd & 7;
    Wq4[nt * 6144 + kc * 256 + c * 8 + kb4] = wq;
}

// ---------------------------------------------------------------------------
// Fused forward — zero-barrier main loop, register-safe shell.
// 256 threads = 4 waves; each wave owns a 32-row strip and loops over all
// 16 chunks of 64 cols (2 n-tiles per chunk, A-fragment expanded once per
// ks and shared by 2 MFMAs). A (binary x) = 384-bit mask in 12 VGPRs/lane.
// B fragments come straight from L2 (fragment-major Wq2, no LDS, no STAGE,
// no per-chunk barriers). launch_bounds(256,4) -> 128-VGPR cap (validated
// no-spill in r8 at ~104; here ~115 live).
// ---------------------------------------------------------------------------
__global__ __launch_bounds__(256, 4) void nnue_fwd(
    const float* __restrict__ x,       // [B][768], values in {0,1}
    const signed char* __restrict__ Wq2,
    const float* __restrict__ amax,
    const float* __restrict__ b_in,    // [1024]
    const float* __restrict__ W_h,     // [8][1024]
    const float* __restrict__ b_h,     // [8]
    const float* __restrict__ W_psqt,  // [768]
    float* __restrict__ out) {         // [B]

    __shared__ int   bmeta[128];
    __shared__ float pmeta[128];

    const int t = threadIdx.x;
    const int l = t & 63, w = t >> 6;   // 4 waves
    const int cl = l & 31;              // row-in-strip / col-in-tile
    const int hi = l >> 5;              // K-half selector
    const size_t row0 = (size_t)blockIdx.x << 7;
    const int r = (w << 5) + cl;        // this lane's A row (0..127)

    // ---- A: load x, pack to BITS (12 regs), popcount + psqt -------------
    u32 Ab[12];
    u32 csum = 0;
    float ps = 0.0f;
    {
        const float4* xr = (const float4*)(x + (row0 + r) * 768);
        const float4* pw = (const float4*)W_psqt;
#define PKB(f) ((__float_as_uint(f.x) >> 29)         |                      \
                ((__float_as_uint(f.y) >> 29) << 8)  |                      \
                ((__float_as_uint(f.z) >> 29) << 16) |                      \
                ((__float_as_uint(f.w) >> 29) << 24))
#define DOT4(f, q) ps = fmaf(f.x, q.x, ps); ps = fmaf(f.y, q.y, ps);        \
                   ps = fmaf(f.z, q.z, ps); ps = fmaf(f.w, q.w, ps);
#pragma unroll
        for (int ks = 0; ks < 24; ++ks) {
            int q4 = (ks << 3) + (hi << 2);     // k = ks*32 + hi*16
            float4 f0 = xr[q4 + 0], f1 = xr[q4 + 1];
            float4 f2 = xr[q4 + 2], f3 = xr[q4 + 3];
            float4 p0 = pw[q4 + 0], p1 = pw[q4 + 1];
            float4 p2 = pw[q4 + 2], p3 = pw[q4 + 3];
            u32 d0 = PKB(f0), d1 = PKB(f1), d2 = PKB(f2), d3 = PKB(f3);
            csum += d0 + d1 + d2 + d3;          // byte-lane sums <= 96
            DOT4(f0, p0) DOT4(f1, p1) DOT4(f2, p2) DOT4(f3, p3)
            // compress 16 offset-bytes (0/1) -> 16 bits, elem j -> bit j
            u32 m16 = ((d0 * 0x01020408u) >> 24)
                    | (((d1 * 0x01020408u) >> 24) << 4)
                    | (((d2 * 0x01020408u) >> 24) << 8)
                    | (((d3 * 0x01020408u) >> 24) << 12);
            Ab[ks >> 1] = (ks & 1) ? (Ab[ks >> 1] | (m16 << 16)) : m16;
        }
#undef DOT4
#undef PKB
    }
    int cnt = (csum & 0xFF) + ((csum >> 8) & 0xFF) +
              ((csum >> 16) & 0xFF) + (csum >> 24);
    cnt += __shfl_xor(cnt, 32);                 // pair (l, l^32) = full row
    ps  += __shfl_xor(ps, 32);
    if (hi == 0) {                              // intra-wave meta (own strip)
        bmeta[r] = (cnt - 1) >> 2;
        pmeta[r] = ps;
    }
    __syncthreads();                            // the ONLY block barrier

    // per-lane epilogue row table: row_in_strip = (g&3) + 8*(g>>2) + 4*hi
    int whoff[16];
#pragma unroll
    for (int g = 0; g < 16; ++g) {
        int er = (w << 5) + (g & 3) + ((g >> 2) << 3) + (hi << 2);
        whoff[g] = bmeta[er] << 10;             // bucket*1024
    }

    const float sc = amax[0] * (1.0f / 127.0f);
    float rs[16];
#pragma unroll
    for (int g = 0; g < 16; ++g) rs[g] = 0.0f;

    // lane's slot within a B fragment: (col, k-half)
    const signed char* bbase = Wq2 + (cl << 5) + (hi << 4);

    // ---- main loop: 16 chunks x 64 cols, B direct from L2, NO barriers --
    for (int c = 0; c < 16; ++c) {
        i32x16 acc0 = {0,0,0,0,0,0,0,0,0,0,0,0,0,0,0,0};
        i32x16 acc1 = {0,0,0,0,0,0,0,0,0,0,0,0,0,0,0,0};
        const signed char* bp0 = bbase + (size_t)(c << 1) * 24576;
        const signed char* bp1 = bp0 + 24576;
#pragma unroll
        for (int ks = 0; ks < 24; ++ks) {
            u32 pair = Ab[ks >> 1];
            asm volatile("" : "+v"(pair));      // defeat cross-chunk CSE
            u32 m = (ks & 1) ? (pair >> 16) : (pair & 0xFFFFu);
            // expand 16 bits -> 16 i8 (bit j -> byte j of the fragment)
            i32x4 af;
            af[0] = (int)(((m         & 0xFu) * 0x00204081u) & 0x01010101u);
            af[1] = (int)((((m >> 4)  & 0xFu) * 0x00204081u) & 0x01010101u);
            af[2] = (int)((((m >> 8)  & 0xFu) * 0x00204081u) & 0x01010101u);
            af[3] = (int)((((m >> 12)       ) * 0x00204081u) & 0x01010101u);
            i32x4 b0 = *(const i32x4*)(bp0 + (ks << 10));
            i32x4 b1 = *(const i32x4*)(bp1 + (ks << 10));
            acc0 = __builtin_amdgcn_mfma_i32_32x32x32_i8(af, b0, acc0, 0, 0, 0);
            acc1 = __builtin_amdgcn_mfma_i32_32x32x32_i8(af, b1, acc1, 0, 0, 0);
        }

        // fused epilogue: both col-tiles -> same per-row dot rs[g]
        const int col0 = (c << 6) + cl;
        const float bi0 = b_in[col0], bi1 = b_in[col0 + 32];
#pragma unroll
        for (int g = 0; g < 16; ++g) {
            float h0 = fminf(fmaxf(fmaf((float)acc0[g], sc, bi0), 0.f), 1.f);
            float h1 = fminf(fmaxf(fmaf((float)acc1[g], sc, bi1), 0.f), 1.f);
            rs[g] = fmaf(h0, W_h[whoff[g] + col0], rs[g]);
            rs[g] = fmaf(h1, W_h[whoff[g] + col0 + 32], rs[g]);
        }
    }

    // ---- reduce over 32 col-lanes (within each hi half), write ----------
#pragma unroll
    for (int g = 0; g < 16; ++g) {
#pragma unroll
        for (int d = 1; d < 32; d <<= 1) rs[g] += __shfl_xor(rs[g], d);
    }
    if (cl == 0) {
#pragma unroll
        for (int g = 0; g < 16; ++g) {
            int er = (w << 5) + (g & 3) + ((g >> 2) << 3) + (hi << 2);
            out[row0 + er] = rs[g] + pmeta[er] + b_h[whoff[g] >> 10];
        }
    }
}

extern "C" void kernel_launch(void* const* d_in, const int* in_sizes, int n_in,
                              void* d_out, int out_size, void* d_ws, size_t ws_size,
                              hipStream_t stream) {
    const float* x      = (const float*)d_in[0];
    const float* W_in   = (const float*)d_in[1];
    const float* b_in   = (const float*)d_in[2];
    const float* W_h    = (const float*)d_in[3];
    const float* b_h    = (const float*)d_in[4];
    const float* W_psqt = (const float*)d_in[5];
    float* out = (float*)d_out;

    float* amax = (float*)d_ws;
    float* part = (float*)((char*)d_ws + 64);
    signed char* Wq2 = (signed char*)d_ws + WQ_OFF;     // 768 KB

    amax_stage1<<<256, 256, 0, stream>>>(W_in, part);
    amax_stage2<<<1, 256, 0, stream>>>(part, amax);
    quant_k<<<1024, 192, 0, stream>>>(W_in, amax, (u32*)Wq2);

    int B = out_size;                   // 65536
    nnue_fwd<<<B / 128, 256, 0, stream>>>(x, Wq2, amax, b_in, W_h, b_h,
                                          W_psqt, out);
}

// Round 11
// 145.284 us; speedup vs baseline: 1.9061x; 1.2200x over previous
//
#include <hip/hip_runtime.h>

typedef unsigned int u32;
typedef int i32x4 __attribute__((ext_vector_type(4)));
typedef int i32x16 __attribute__((ext_vector_type(16)));

// ws layout (bytes):
//   [0..3]      amax (float)
//   [64..1087]  256 partial maxima (float)
//   [2048..]    Wq2: fragment-major i8 weights, 768 KB:
//               addr = nt*24576 + kc*1024 + c*32 + kb
//               (n = nt*32+c in [0,1024), k = kc*32+kb in [0,768))
//               -> a wave's MFMA B-fragment (32 cols x 32 k) is 1 KB,
//                  one coalesced dwordx4 per lane, L2-resident.
#define WQ_OFF 2048

// ---------------------------------------------------------------------------
// absmax two-stage tree (no atomics)
// ---------------------------------------------------------------------------
__global__ __launch_bounds__(256) void amax_stage1(const float* __restrict__ W,
                                                   float* __restrict__ part) {
    int t = blockIdx.x * 256 + threadIdx.x;
    float v = 0.0f;
#pragma unroll
    for (int k = 0; k < 12; ++k) v = fmaxf(v, fabsf(W[t + (k << 16)]));
#pragma unroll
    for (int d = 32; d >= 1; d >>= 1) v = fmaxf(v, __shfl_xor(v, d));
    __shared__ float sm[4];
    if ((threadIdx.x & 63) == 0) sm[threadIdx.x >> 6] = v;
    __syncthreads();
    if (threadIdx.x == 0)
        part[blockIdx.x] = fmaxf(fmaxf(sm[0], sm[1]), fmaxf(sm[2], sm[3]));
}

__global__ __launch_bounds__(256) void amax_stage2(const float* __restrict__ part,
                                                   float* __restrict__ amax) {
    float v = part[threadIdx.x];
#pragma unroll
    for (int d = 32; d >= 1; d >>= 1) v = fmaxf(v, __shfl_xor(v, d));
    __shared__ float sm[4];
    if ((threadIdx.x & 63) == 0) sm[threadIdx.x >> 6] = v;
    __syncthreads();
    if (threadIdx.x == 0)
        amax[0] = fmaxf(fmaxf(sm[0], sm[1]), fmaxf(sm[2], sm[3]));
}

// ---------------------------------------------------------------------------
// quantize W_in [1024][768] f32 -> Wq2 fragment-major i8 (validated r9/r10)
// ---------------------------------------------------------------------------
__global__ __launch_bounds__(192) void quant_k(const float* __restrict__ W,
                                               const float* __restrict__ amax,
                                               u32* __restrict__ Wq4) {
    const int n = blockIdx.x, kd = threadIdx.x;     // kd: dword index 0..191
    float s = 127.0f / amax[0];
    float4 v = ((const float4*)(W + n * 768))[kd];
    int a0 = (int)rintf(v.x * s), a1 = (int)rintf(v.y * s);
    int a2 = (int)rintf(v.z * s), a3 = (int)rintf(v.w * s);
    u32 wq = (u32)(a0 & 0xFF) | ((u32)(a1 & 0xFF) << 8) |
             ((u32)(a2 & 0xFF) << 16) | ((u32)(a3 & 0xFF) << 24);
    const int nt = n >> 5, c = n & 31, kc = kd >> 3, kb4 = kd & 7;
    Wq4[nt * 6144 + kc * 256 + c * 8 + kb4] = wq;
}

// ---------------------------------------------------------------------------
// Fused forward — zero-barrier main loop, occupancy-fixed.
// M=64 rows/block, grid 1024 -> 4 blocks/CU, 16 waves/CU (50% cap).
// 256 threads = 4 waves = 2 row-strips x 2 N-halves; each wave: 8 chunks
// of 64 cols (2 n-tiles), A expanded in-loop from 12-dword bitmask,
// B direct from L2 (fragment-major Wq2). A-phase is cooperative (4
// threads/row) via a 6 KB LDS bit-panel -> x read once per block.
// amdgpu_waves_per_eu(4,4): pins the allocator to a 128-VGPR budget
// (r10's failure: tiny LDS made it target 8 waves/EU -> 64 regs -> spill).
// ---------------------------------------------------------------------------
__global__ __launch_bounds__(256)
__attribute__((amdgpu_waves_per_eu(4, 4)))
void nnue_fwd(
    const float* __restrict__ x,       // [B][768], values in {0,1}
    const signed char* __restrict__ Wq2,
    const float* __restrict__ amax,
    const float* __restrict__ b_in,    // [1024]
    const float* __restrict__ W_h,     // [8][1024]
    const float* __restrict__ b_h,     // [8]
    const float* __restrict__ W_psqt,  // [768]
    float* __restrict__ out) {         // [B]

    __shared__ u32   abits[64][2][12]; // [row][k-half][dword]  6 KB
    __shared__ int   bmeta[64];
    __shared__ float pmeta[64];
    __shared__ float comb[64][2];

    const int t = threadIdx.x;
    const size_t row0 = (size_t)blockIdx.x << 6;

    // ---- A phase: 4 threads per row pack x-bits, popcount, psqt ---------
    {
        const int row = t >> 2, q = t & 3;          // q: K-quarter (192 k)
        const float4* xr = (const float4*)(x + (row0 + row) * 768) + q * 48;
        const float4* pw = (const float4*)W_psqt + q * 48;
        u32 csum = 0;
        float ps = 0.0f;
#define PKB(f) ((__float_as_uint(f.x) >> 29)         |                      \
                ((__float_as_uint(f.y) >> 29) << 8)  |                      \
                ((__float_as_uint(f.z) >> 29) << 16) |                      \
                ((__float_as_uint(f.w) >> 29) << 24))
#pragma unroll
        for (int i3 = 0; i3 < 3; ++i3) {
#pragma unroll
            for (int hh = 0; hh < 2; ++hh) {
                u32 dw = 0;
#pragma unroll
                for (int dl = 0; dl < 2; ++dl) {
                    u32 m16 = 0;
#pragma unroll
                    for (int jj = 0; jj < 4; ++jj) {
                        // float4 idx: k_loc = 64*i3 + 32*dl + 16*hh + 4*jj
                        int fi = i3 * 16 + dl * 8 + hh * 4 + jj;
                        float4 f = xr[fi], p = pw[fi];
                        u32 d = PKB(f);
                        csum += d;                  // byte sums <= 48
                        ps = fmaf(f.x, p.x, ps); ps = fmaf(f.y, p.y, ps);
                        ps = fmaf(f.z, p.z, ps); ps = fmaf(f.w, p.w, ps);
                        m16 |= ((d * 0x01020408u) >> 24) << (jj * 4);
                    }
                    dw |= m16 << (dl * 16);
                }
                abits[row][hh][3 * q + i3] = dw;    // dword i: ks=2i,2i+1
            }
        }
#undef PKB
        int cnt = (csum & 0xFF) + ((csum >> 8) & 0xFF) +
                  ((csum >> 16) & 0xFF) + (csum >> 24);
        cnt += __shfl_xor(cnt, 1); cnt += __shfl_xor(cnt, 2);
        ps  += __shfl_xor(ps, 1);  ps  += __shfl_xor(ps, 2);
        if (q == 0) { bmeta[row] = (cnt - 1) >> 2; pmeta[row] = ps; }
    }
    __syncthreads();            // the ONLY pre-loop barrier

    // ---- per-lane setup -------------------------------------------------
    const int l = t & 63, w = t >> 6;
    const int cl = l & 31, hi = l >> 5;
    const int strip = w >> 1, nh = w & 1;   // row-strip, N-half
    const int r = (strip << 5) + cl;        // this lane's A row (0..63)

    u32 Ab[12];
    {
        uint4 A0 = *(const uint4*)&abits[r][hi][0];
        uint4 A1 = *(const uint4*)&abits[r][hi][4];
        uint4 A2 = *(const uint4*)&abits[r][hi][8];
        Ab[0] = A0.x; Ab[1] = A0.y; Ab[2]  = A0.z; Ab[3]  = A0.w;
        Ab[4] = A1.x; Ab[5] = A1.y; Ab[6]  = A1.z; Ab[7]  = A1.w;
        Ab[8] = A2.x; Ab[9] = A2.y; Ab[10] = A2.z; Ab[11] = A2.w;
    }

    int whoff[16];
#pragma unroll
    for (int g = 0; g < 16; ++g) {
        int er = (strip << 5) + (g & 3) + ((g >> 2) << 3) + (hi << 2);
        whoff[g] = bmeta[er] << 10;             // bucket * 1024
    }

    const float sc = amax[0] * (1.0f / 127.0f);
    float rs[16];
#pragma unroll
    for (int g = 0; g < 16; ++g) rs[g] = 0.0f;

    // lane's slot within a B fragment: (col, k-half)
    const signed char* bbase = Wq2 + (cl << 5) + (hi << 4);

    // ---- main loop: 8 chunks x 64 cols, B direct from L2, NO barriers ---
    for (int c = 0; c < 8; ++c) {
        const int cc = (nh << 3) + c;           // global chunk 0..15
        i32x16 acc0 = {0,0,0,0,0,0,0,0,0,0,0,0,0,0,0,0};
        i32x16 acc1 = {0,0,0,0,0,0,0,0,0,0,0,0,0,0,0,0};
        const signed char* bp0 = bbase + (size_t)(cc << 1) * 24576;
        const signed char* bp1 = bp0 + 24576;
#pragma unroll
        for (int ks = 0; ks < 24; ++ks) {
            u32 pair = Ab[ks >> 1];
            asm volatile("" : "+v"(pair));      // defeat cross-chunk CSE
            u32 m = (ks & 1) ? (pair >> 16) : (pair & 0xFFFFu);
            // expand 16 bits -> 16 i8 (bit j -> byte j of the fragment)
            i32x4 af;
            af[0] = (int)(((m         & 0xFu) * 0x00204081u) & 0x01010101u);
            af[1] = (int)((((m >> 4)  & 0xFu) * 0x00204081u) & 0x01010101u);
            af[2] = (int)((((m >> 8)  & 0xFu) * 0x00204081u) & 0x01010101u);
            af[3] = (int)((((m >> 12)       ) * 0x00204081u) & 0x01010101u);
            i32x4 b0 = *(const i32x4*)(bp0 + (ks << 10));
            i32x4 b1 = *(const i32x4*)(bp1 + (ks << 10));
            acc0 = __builtin_amdgcn_mfma_i32_32x32x32_i8(af, b0, acc0, 0, 0, 0);
            acc1 = __builtin_amdgcn_mfma_i32_32x32x32_i8(af, b1, acc1, 0, 0, 0);
        }

        // fused epilogue: both col-tiles -> same per-row dot rs[g]
        const int col0 = (cc << 6) + cl;
        const float bi0 = b_in[col0], bi1 = b_in[col0 + 32];
#pragma unroll
        for (int g = 0; g < 16; ++g) {
            float h0 = fminf(fmaxf(fmaf((float)acc0[g], sc, bi0), 0.f), 1.f);
            float h1 = fminf(fmaxf(fmaf((float)acc1[g], sc, bi1), 0.f), 1.f);
            rs[g] = fmaf(h0, W_h[whoff[g] + col0], rs[g]);
            rs[g] = fmaf(h1, W_h[whoff[g] + col0 + 32], rs[g]);
        }
    }

    // ---- reduce over 32 col-lanes, combine the two N-halves -------------
#pragma unroll
    for (int g = 0; g < 16; ++g) {
#pragma unroll
        for (int d = 1; d < 32; d <<= 1) rs[g] += __shfl_xor(rs[g], d);
    }
    if (cl == 0) {
#pragma unroll
        for (int g = 0; g < 16; ++g) {
            int er = (strip << 5) + (g & 3) + ((g >> 2) << 3) + (hi << 2);
            comb[er][nh] = rs[g];
        }
    }
    __syncthreads();
    if (t < 64) {
        out[row0 + t] = comb[t][0] + comb[t][1] + pmeta[t] + b_h[bmeta[t]];
    }
}

extern "C" void kernel_launch(void* const* d_in, const int* in_sizes, int n_in,
                              void* d_out, int out_size, void* d_ws, size_t ws_size,
                              hipStream_t stream) {
    const float* x      = (const float*)d_in[0];
    const float* W_in   = (const float*)d_in[1];
    const float* b_in   = (const float*)d_in[2];
    const float* W_h    = (const float*)d_in[3];
    const float* b_h    = (const float*)d_in[4];
    const float* W_psqt = (const float*)d_in[5];
    float* out = (float*)d_out;

    float* amax = (float*)d_ws;
    float* part = (float*)((char*)d_ws + 64);
    signed char* Wq2 = (signed char*)d_ws + WQ_OFF;     // 768 KB

    amax_stage1<<<256, 256, 0, stream>>>(W_in, part);
    amax_stage2<<<1, 256, 0, stream>>>(part, amax);
    quant_k<<<1024, 192, 0, stream>>>(W_in, amax, (u32*)Wq2);

    int B = out_size;                   // 65536
    nnue_fwd<<<B / 64, 256, 0, stream>>>(x, Wq2, amax, b_in, W_h, b_h,
                                         W_psqt, out);
}

// Round 12
// 100.182 us; speedup vs baseline: 2.7642x; 1.4502x over previous
//
#include <hip/hip_runtime.h>

typedef unsigned int u32;
typedef int i32x4 __attribute__((ext_vector_type(4)));
typedef int i32x16 __attribute__((ext_vector_type(16)));

// ws layout (bytes):
//   [0..3]      amax (float)
//   [64..1087]  256 partial maxima (float)
//   [2048..]    Wq2: fragment-major i8 weights, 768 KB:
//               addr = nt*24576 + kc*1024 + col*32 + kb
//               (n = nt*32+col in [0,1024), k = kc*32+kb in [0,768))
#define WQ_OFF 2048

__device__ __forceinline__ void gld16(const void* g, void* l) {
    __builtin_amdgcn_global_load_lds(
        (const __attribute__((address_space(1))) void*)g,
        (__attribute__((address_space(3))) void*)l, 16, 0, 0);
}

// ---------------------------------------------------------------------------
// absmax two-stage tree (no atomics)
// ---------------------------------------------------------------------------
__global__ __launch_bounds__(256) void amax_stage1(const float* __restrict__ W,
                                                   float* __restrict__ part) {
    int t = blockIdx.x * 256 + threadIdx.x;
    float v = 0.0f;
#pragma unroll
    for (int k = 0; k < 12; ++k) v = fmaxf(v, fabsf(W[t + (k << 16)]));
#pragma unroll
    for (int d = 32; d >= 1; d >>= 1) v = fmaxf(v, __shfl_xor(v, d));
    __shared__ float sm[4];
    if ((threadIdx.x & 63) == 0) sm[threadIdx.x >> 6] = v;
    __syncthreads();
    if (threadIdx.x == 0)
        part[blockIdx.x] = fmaxf(fmaxf(sm[0], sm[1]), fmaxf(sm[2], sm[3]));
}

__global__ __launch_bounds__(256) void amax_stage2(const float* __restrict__ part,
                                                   float* __restrict__ amax) {
    float v = part[threadIdx.x];
#pragma unroll
    for (int d = 32; d >= 1; d >>= 1) v = fmaxf(v, __shfl_xor(v, d));
    __shared__ float sm[4];
    if ((threadIdx.x & 63) == 0) sm[threadIdx.x >> 6] = v;
    __syncthreads();
    if (threadIdx.x == 0)
        amax[0] = fmaxf(fmaxf(sm[0], sm[1]), fmaxf(sm[2], sm[3]));
}

// ---------------------------------------------------------------------------
// quantize W_in [1024][768] f32 -> Wq2 fragment-major i8 (validated r9-r11)
// ---------------------------------------------------------------------------
__global__ __launch_bounds__(192) void quant_k(const float* __restrict__ W,
                                               const float* __restrict__ amax,
                                               u32* __restrict__ Wq4) {
    const int n = blockIdx.x, kd = threadIdx.x;     // kd: dword index 0..191
    float s = 127.0f / amax[0];
    float4 v = ((const float4*)(W + n * 768))[kd];
    int a0 = (int)rintf(v.x * s), a1 = (int)rintf(v.y * s);
    int a2 = (int)rintf(v.z * s), a3 = (int)rintf(v.w * s);
    u32 wq = (u32)(a0 & 0xFF) | ((u32)(a1 & 0xFF) << 8) |
             ((u32)(a2 & 0xFF) << 16) | ((u32)(a3 & 0xFF) << 24);
    const int nt = n >> 5, c = n & 31, kc = kd >> 3, kb4 = kd & 7;
    Wq4[nt * 6144 + kc * 256 + c * 8 + kb4] = wq;
}

// ---------------------------------------------------------------------------
// Fused forward — 2-phase pipelined LDS staging (T3 minimum recipe):
// STAGE(next) issued BEFORE compute of current, double buffer, ONE barrier
// per 24 KB stage. M=128 rows/block, 256 thr = 4 waves, each wave = one
// 32-row strip x full N (B shared by all waves). 32 stages = 16 chunks of
// 64 cols x 2 K-halves (384 k each). A (binary x) = 384-bit mask in 12
// VGPRs/lane, expanded to i8 frags in-loop (af shared by 2 MFMAs).
// grid 512 -> 2 blocks/CU (LDS 50 KB); amdgpu_waves_per_eu(2,2) pins the
// allocator to a 256-reg budget (2 waves/SIMD is the LDS-set ceiling anyway).
// ---------------------------------------------------------------------------
__global__ __launch_bounds__(256)
__attribute__((amdgpu_waves_per_eu(2, 2)))
void nnue_fwd(
    const float* __restrict__ x,       // [B][768], values in {0,1}
    const signed char* __restrict__ Wq2,
    const float* __restrict__ amax,
    const float* __restrict__ b_in,    // [1024]
    const float* __restrict__ W_h,     // [8][1024]
    const float* __restrict__ b_h,     // [8]
    const float* __restrict__ W_psqt,  // [768]
    float* __restrict__ out) {         // [B]

    __shared__ __align__(16) signed char bufs[2][24576];  // [nt 2][kc 12][1 KB]
    __shared__ int   bmeta[128];
    __shared__ float pmeta[128];

    const int t = threadIdx.x;
    const int l = t & 63, w = t >> 6;   // 4 waves = 4 row-strips
    const int cl = l & 31;              // row-in-strip / col-in-tile
    const int hi = l >> 5;              // K-half-of-fragment selector
    const size_t row0 = (size_t)blockIdx.x << 7;
    const int r = (w << 5) + cl;        // this lane's A row (0..127)

    // STAGE(dst, c_, h_): copy chunk c_ (64 cols), K-half h_ (384 k) -> dst.
    // Wave w stages slabs j = w*6 .. w*6+5 (slab = 1 KB kc-slice of an nt).
    // LDS dest is wave-uniform; per-lane global src supplies lane*16 bytes.
#define STAGE(dst, c_, h_)                                                  \
    _Pragma("unroll")                                                       \
    for (int i = 0; i < 6; ++i) {                                           \
        int jj = w * 6 + i;                 /* 0..23 */                     \
        int ntl = jj >= 12 ? 1 : 0;                                         \
        int kcl = jj - ntl * 12;                                            \
        gld16(Wq2 + (size_t)(((c_) << 1) + ntl) * 24576                     \
                  + (size_t)((h_) * 12 + kcl) * 1024 + (l << 4),            \
              (signed char*)(dst) + jj * 1024);                             \
    }

    STAGE(bufs[0], 0, 0)        // stage 0 in flight under the A-phase

    // ---- A: load x, pack to BITS (12 regs), popcount + psqt -------------
    u32 Ab[12];
    u32 csum = 0;
    float ps = 0.0f;
    {
        const float4* xr = (const float4*)(x + (row0 + r) * 768);
        const float4* pw = (const float4*)W_psqt;
#define PKB(f) ((__float_as_uint(f.x) >> 29)         |                      \
                ((__float_as_uint(f.y) >> 29) << 8)  |                      \
                ((__float_as_uint(f.z) >> 29) << 16) |                      \
                ((__float_as_uint(f.w) >> 29) << 24))
#define DOT4(f, q) ps = fmaf(f.x, q.x, ps); ps = fmaf(f.y, q.y, ps);        \
                   ps = fmaf(f.z, q.z, ps); ps = fmaf(f.w, q.w, ps);
#pragma unroll
        for (int ks = 0; ks < 24; ++ks) {
            int q4 = (ks << 3) + (hi << 2);     // k = ks*32 + hi*16
            float4 f0 = xr[q4 + 0], f1 = xr[q4 + 1];
            float4 f2 = xr[q4 + 2], f3 = xr[q4 + 3];
            float4 p0 = pw[q4 + 0], p1 = pw[q4 + 1];
            float4 p2 = pw[q4 + 2], p3 = pw[q4 + 3];
            u32 d0 = PKB(f0), d1 = PKB(f1), d2 = PKB(f2), d3 = PKB(f3);
            csum += d0 + d1 + d2 + d3;          // byte-lane sums <= 96
            DOT4(f0, p0) DOT4(f1, p1) DOT4(f2, p2) DOT4(f3, p3)
            u32 m16 = ((d0 * 0x01020408u) >> 24)
                    | (((d1 * 0x01020408u) >> 24) << 4)
                    | (((d2 * 0x01020408u) >> 24) << 8)
                    | (((d3 * 0x01020408u) >> 24) << 12);
            Ab[ks >> 1] = (ks & 1) ? (Ab[ks >> 1] | (m16 << 16)) : m16;
        }
#undef DOT4
#undef PKB
    }
    int cnt = (csum & 0xFF) + ((csum >> 8) & 0xFF) +
              ((csum >> 16) & 0xFF) + (csum >> 24);
    cnt += __shfl_xor(cnt, 32);                 // pair (l, l^32) = full row
    ps  += __shfl_xor(ps, 32);
    if (hi == 0) {
        bmeta[r] = (cnt - 1) >> 2;
        pmeta[r] = ps;
    }
    __syncthreads();            // meta visible; stage 0 landed (vmcnt drain)

    int whoff[16];
#pragma unroll
    for (int g = 0; g < 16; ++g) {
        int er = (w << 5) + (g & 3) + ((g >> 2) << 3) + (hi << 2);
        whoff[g] = bmeta[er] << 10;             // bucket * 1024
    }

    const float sc = amax[0] * (1.0f / 127.0f);
    float rs[16];
#pragma unroll
    for (int g = 0; g < 16; ++g) rs[g] = 0.0f;

#define COMPUTE(buf, h_)                                                    \
    {                                                                       \
        const signed char* bb = (const signed char*)(buf)                   \
                                + (cl << 5) + (hi << 4);                    \
        _Pragma("unroll")                                                   \
        for (int kc = 0; kc < 12; ++kc) {                                   \
            int ks = (h_) * 12 + kc;                                        \
            u32 pair = Ab[ks >> 1];                                         \
            asm volatile("" : "+v"(pair));      /* defeat hoist/CSE */      \
            u32 m = (ks & 1) ? (pair >> 16) : (pair & 0xFFFFu);             \
            i32x4 af;                                                       \
            af[0] = (int)(((m        & 0xFu) * 0x00204081u) & 0x01010101u); \
            af[1] = (int)((((m >> 4) & 0xFu) * 0x00204081u) & 0x01010101u); \
            af[2] = (int)((((m >> 8) & 0xFu) * 0x00204081u) & 0x01010101u); \
            af[3] = (int)((((m >> 12)      ) * 0x00204081u) & 0x01010101u); \
            i32x4 b0 = *(const i32x4*)(bb + (kc << 10));                    \
            i32x4 b1 = *(const i32x4*)(bb + 12288 + (kc << 10));            \
            acc0 = __builtin_amdgcn_mfma_i32_32x32x32_i8(af, b0, acc0, 0, 0, 0); \
            acc1 = __builtin_amdgcn_mfma_i32_32x32x32_i8(af, b1, acc1, 0, 0, 0); \
        }                                                                   \
    }

    // ---- main loop: 16 chunks x (2 K-half stages), 2 barriers/chunk -----
    for (int c = 0; c < 16; ++c) {
        i32x16 acc0 = {0,0,0,0,0,0,0,0,0,0,0,0,0,0,0,0};
        i32x16 acc1 = {0,0,0,0,0,0,0,0,0,0,0,0,0,0,0,0};

        // stage (c, half 1) into bufs[1]; compute (c, half 0) from bufs[0]
        STAGE(bufs[1], c, 1)
        COMPUTE(bufs[0], 0)
        __syncthreads();

        // stage (c+1, half 0) into bufs[0]; compute (c, half 1) from bufs[1]
        if (c < 15) STAGE(bufs[0], c + 1, 0)
        COMPUTE(bufs[1], 1)

        // fused epilogue (regs + L1-hot globals; covers the stage latency)
        const int col0 = (c << 6) + cl;
        const float bi0 = b_in[col0], bi1 = b_in[col0 + 32];
#pragma unroll
        for (int g = 0; g < 16; ++g) {
            float h0 = fminf(fmaxf(fmaf((float)acc0[g], sc, bi0), 0.f), 1.f);
            float h1 = fminf(fmaxf(fmaf((float)acc1[g], sc, bi1), 0.f), 1.f);
            rs[g] = fmaf(h0, W_h[whoff[g] + col0], rs[g]);
            rs[g] = fmaf(h1, W_h[whoff[g] + col0 + 32], rs[g]);
        }
        __syncthreads();
    }
#undef COMPUTE
#undef STAGE

    // ---- reduce over 32 col-lanes, write --------------------------------
#pragma unroll
    for (int g = 0; g < 16; ++g) {
#pragma unroll
        for (int d = 1; d < 32; d <<= 1) rs[g] += __shfl_xor(rs[g], d);
    }
    if (cl == 0) {
#pragma unroll
        for (int g = 0; g < 16; ++g) {
            int er = (w << 5) + (g & 3) + ((g >> 2) << 3) + (hi << 2);
            out[row0 + er] = rs[g] + pmeta[er] + b_h[whoff[g] >> 10];
        }
    }
}

extern "C" void kernel_launch(void* const* d_in, const int* in_sizes, int n_in,
                              void* d_out, int out_size, void* d_ws, size_t ws_size,
                              hipStream_t stream) {
    const float* x      = (const float*)d_in[0];
    const float* W_in   = (const float*)d_in[1];
    const float* b_in   = (const float*)d_in[2];
    const float* W_h    = (const float*)d_in[3];
    const float* b_h    = (const float*)d_in[4];
    const float* W_psqt = (const float*)d_in[5];
    float* out = (float*)d_out;

    float* amax = (float*)d_ws;
    float* part = (float*)((char*)d_ws + 64);
    signed char* Wq2 = (signed char*)d_ws + WQ_OFF;     // 768 KB

    amax_stage1<<<256, 256, 0, stream>>>(W_in, part);
    amax_stage2<<<1, 256, 0, stream>>>(part, amax);
    quant_k<<<1024, 192, 0, stream>>>(W_in, amax, (u32*)Wq2);

    int B = out_size;                   // 65536
    nnue_fwd<<<B / 128, 256, 0, stream>>>(x, Wq2, amax, b_in, W_h, b_h,
                                          W_psqt, out);
}